// Round 12
// baseline (173.003 us; speedup 1.0000x reference)
//
#include <hip/hip_runtime.h>
#include <math.h>

#define ACT_SHIFT -4.5951198501345889f
#define NSLOTMAX (4096*446)

typedef _Float16 f16;
typedef f16 f16x8 __attribute__((ext_vector_type(8)));
typedef float f32x4 __attribute__((ext_vector_type(4)));
typedef float f32x16 __attribute__((ext_vector_type(16)));

// ---- workspace layout (bytes) ----
#define OFF_CNT  0                          // int cnt, int qhead
#define OFF_RAYI 256                        // int4 * 4096
#define OFF_RAYF (OFF_RAYI + 4096*16)       // float2 * 4096 {tmin, nrm}
#define OFF_EMBW (OFF_RAYF + 4096*8)        // float * 4096*64
#define OFF_WTS  (OFF_EMBW + 4096*64*4)     // f16 * 46080 (XOR-swizzled layout)
#define OFF_BIAS (OFF_WTS + 92160)          // float * 1408 (11 layers x 128)
#define OFF_SLOT (OFF_BIAS + 8192)          // int * NSLOTMAX
#define OFF_WS4H (OFF_SLOT + NSLOTMAX*4)    // ushort4 * NSLOTMAX

// weight slab offsets (f16 elements), Wt[dout][KP] row-major, XOR-swizzled
#define W_MW1 0        /* 128 x 16  */
#define W_MW2 2048     /* 128 x 128 */
#define W_MW3 18432    /* 32  x 128 */
#define W_FV  22528    /* 64  x 32  */
#define W_P1  24576    /* 64  x 64  */
#define W_P2  28672    /* 64  x 64  */
#define W_P3  32768    /* 32  x 64  (douts 16-31 zero-pad) */
#define W_D1  34816    /* 64  x 16  (k=0 zero col) */
#define W_D2  35840    /* 64  x 64  */
#define W_D3  39936    /* 64  x 64  */
#define W_D4  44032    /* 32  x 64  (douts 3-31 zero-pad) */
#define W_TOT 46080

static __device__ __forceinline__ unsigned short f2h(float x) {
  f16 h = (f16)x; return *(unsigned short*)&h;
}
static __device__ __forceinline__ float h2f(unsigned short u) {
  return (float)(*(f16*)&u);
}
static __device__ __forceinline__ unsigned pack2(float a, float b) {
  f16 ha = (f16)a, hb = (f16)b;
  unsigned short ua, ub;
  __builtin_memcpy(&ua, &ha, 2); __builtin_memcpy(&ub, &hb, 2);
  return (unsigned)ua | ((unsigned)ub << 16);
}
static __device__ __forceinline__ f16x8 mkb(unsigned w0, unsigned w1,
                                            unsigned w2, unsigned w3) {
  union { unsigned u[4]; f16x8 h; } x;
  x.u[0] = w0; x.u[1] = w1; x.u[2] = w2; x.u[3] = w3;
  return x.h;
}

static __device__ __forceinline__ void sample_point(
    float ox, float oy, float oz, float dx, float dy, float dz,
    float tmin, float nrm, int s, float& px, float& py, float& pz) {
  float ix = tmin + (0.0078125f * (float)s) / nrm;
  px = ox + dx * ix; py = oy + dy * ix; pz = oz + dz * ix;
}
static __device__ __forceinline__ int in_box(float px, float py, float pz) {
  return !(px < -1.f || px > 1.f || py < -1.f || py > 1.f ||
           pz < -1.f || pz > 1.f);
}

static __device__ __forceinline__ bool ray_setup(
    const float* rays_o, const float* rays_d, int r,
    float& ox, float& oy, float& oz, float& dx, float& dy, float& dz,
    float& tmin, float& nrm) {
  ox = rays_o[r*3+0]; oy = rays_o[r*3+1]; oz = rays_o[r*3+2];
  dx = rays_d[r*3+0]; dy = rays_d[r*3+1]; dz = rays_d[r*3+2];
  const float vx = (dx == 0.0f) ? 1e-6f : dx;
  const float vy = (dy == 0.0f) ? 1e-6f : dy;
  const float vz = (dz == 0.0f) ? 1e-6f : dz;
  const float rax = ( 1.0f - ox) / vx, rbx = (-1.0f - ox) / vx;
  const float ray_ = ( 1.0f - oy) / vy, rby = (-1.0f - oy) / vy;
  const float raz = ( 1.0f - oz) / vz, rbz = (-1.0f - oz) / vz;
  tmin = fmaxf(fmaxf(fminf(rax,rbx), fminf(ray_,rby)), fminf(raz,rbz));
  tmin = fminf(fmaxf(tmin, 0.2f), 3.0f);
  float tmax = fminf(fminf(fmaxf(rax,rbx), fmaxf(ray_,rby)), fmaxf(raz,rbz));
  tmax = fminf(fmaxf(tmax, 0.2f), 3.0f);
  nrm = sqrtf(dx*dx + dy*dy + dz*dz);
  return tmax <= tmin;  // miss
}

// ============ kernel 1: analytic per-ray valid sample range (superset) ========
extern "C" __global__ void __launch_bounds__(256)
k_setup(const float* __restrict__ rays_o, const float* __restrict__ rays_d,
        int* __restrict__ cnt, int4* __restrict__ rayi,
        float2* __restrict__ rayf) {
  int r = blockIdx.x * 256 + threadIdx.x;
  if (r >= 4096) return;
  float ox,oy,oz,dx,dy,dz,tmin,nrm;
  bool miss = ray_setup(rays_o, rays_d, r, ox,oy,oz,dx,dy,dz, tmin, nrm);
  rayf[r] = make_float2(tmin, nrm);
  if (miss) { rayi[r] = make_int4(0,0,0,0); return; }

  float lo = -1e30f, hi = 1e30f;
  float o3[3] = {ox,oy,oz}, d3[3] = {dx,dy,dz};
#pragma unroll
  for (int c = 0; c < 3; ++c) {
    float o = o3[c], d = d3[c];
    if (d == 0.0f) {
      if (o < -1.f || o > 1.f) { lo = 1e30f; hi = -1e30f; }
    } else {
      float t1 = (-1.f - o) / d, t2 = (1.f - o) / d;
      lo = fmaxf(lo, fminf(t1, t2));
      hi = fminf(hi, fmaxf(t1, t2));
    }
  }
  float k = 0.0078125f / nrm;
  float sf = (lo - tmin) / k - 1.0f;
  float lf = (hi - tmin) / k + 1.0f;
  int first = (int)ceilf (fmaxf(0.f,  fminf(445.f, sf)));
  int last  = (int)floorf(fmaxf(-1.f, fminf(445.f, lf)));
  int n_s = (lf >= sf && last >= first) ? (last - first + 1) : 0;
  int base = 0;
  if (n_s > 0) base = atomicAdd(cnt, n_s);
  rayi[r] = make_int4(base, first, n_s, 0);
}

// ============ kernel 2 (fused aux): embW + slot fill + weight/bias pack =======
extern "C" __global__ void __launch_bounds__(256)
k_aux(const float* __restrict__ viewdirs, const int4* __restrict__ rayi,
      int* __restrict__ slot_map,
      const float* __restrict__ mW1, const float* __restrict__ mW2,
      const float* __restrict__ mW3, const float* __restrict__ fv,
      const float* __restrict__ pW1, const float* __restrict__ pW2,
      const float* __restrict__ pW3, const float* __restrict__ dW1,
      const float* __restrict__ dW2, const float* __restrict__ dW3,
      const float* __restrict__ dW4,
      const float* __restrict__ mb1, const float* __restrict__ mb2,
      const float* __restrict__ mb3, const float* __restrict__ pb1,
      const float* __restrict__ pb2, const float* __restrict__ pb3,
      const float* __restrict__ db1, const float* __restrict__ db2,
      const float* __restrict__ db3, const float* __restrict__ db4,
      f16* __restrict__ wts, float* __restrict__ bias,
      float* __restrict__ embW) {
  const int b = blockIdx.x, t = threadIdx.x;
  if (b < 1024) {                       // ---- embW (dir-embed folded into dW1)
    int idx = b * 256 + t;
    int ray = idx >> 6, o = idx & 63;
    float v0 = viewdirs[ray*3+0], v1 = viewdirs[ray*3+1], v2 = viewdirs[ray*3+2];
    float acc = db1[o];
    acc = fmaf(v0, dW1[15*64+o], acc);
    acc = fmaf(v1, dW1[16*64+o], acc);
    acc = fmaf(v2, dW1[17*64+o], acc);
#pragma unroll
    for (int fr = 0; fr < 6; ++fr) {
      float f = (float)(1 << fr);
      int rb = 18 + fr*6;
      acc = fmaf(sinf(v0*f), dW1[(rb+0)*64+o], acc);
      acc = fmaf(sinf(v1*f), dW1[(rb+1)*64+o], acc);
      acc = fmaf(sinf(v2*f), dW1[(rb+2)*64+o], acc);
      acc = fmaf(cosf(v0*f), dW1[(rb+3)*64+o], acc);
      acc = fmaf(cosf(v1*f), dW1[(rb+4)*64+o], acc);
      acc = fmaf(cosf(v2*f), dW1[(rb+5)*64+o], acc);
    }
    embW[idx] = acc;
  } else if (b < 1280) {                // ---- slot_map fill (16 rays/block)
    int ray = (b - 1024) * 16 + (t >> 4);
    int4 ri = rayi[ray];
    for (int i = t & 15; i < ri.z; i += 16)
      slot_map[ri.x + i] = (ray << 9) | (ri.y + i);
  } else if (b < 1460) {                // ---- weight pack, swizzled
    int i = (b - 1280) * 256 + t;
    if (i >= W_TOT) return;
    float v = 0.f; int l, o, k, base, KP;
    if (i < W_MW2)      { base=W_MW1; KP=16;  l=i-base; o=l>>4; k=l&15;  if (k<4)  v = mW1[k*128+o]; }
    else if (i < W_MW3) { base=W_MW2; KP=128; l=i-base; o=l>>7; k=l&127; v = mW2[k*128+o]; }
    else if (i < W_FV)  { base=W_MW3; KP=128; l=i-base; o=l>>7; k=l&127; v = mW3[k*32+o]; }
    else if (i < W_P1)  { base=W_FV;  KP=32;  l=i-base; o=l>>5; k=l&31;  v = fv[k*64+o]; }
    else if (i < W_P2)  { base=W_P1;  KP=64;  l=i-base; o=l>>6; k=l&63;  v = pW1[k*64+o]; }
    else if (i < W_P3)  { base=W_P2;  KP=64;  l=i-base; o=l>>6; k=l&63;  v = pW2[k*64+o]; }
    else if (i < W_D1)  { base=W_P3;  KP=64;  l=i-base; o=l>>6; k=l&63;  if (o<16) v = pW3[k*16+o]; }
    else if (i < W_D2)  { base=W_D1;  KP=16;  l=i-base; o=l>>4; k=l&15;  if (k>=1) v = dW1[(k-1)*64+o]; }
    else if (i < W_D3)  { base=W_D2;  KP=64;  l=i-base; o=l>>6; k=l&63;  v = dW2[k*64+o]; }
    else if (i < W_D4)  { base=W_D3;  KP=64;  l=i-base; o=l>>6; k=l&63;  v = dW3[k*64+o]; }
    else                { base=W_D4;  KP=64;  l=i-base; o=l>>6; k=l&63;  if (o<3)  v = dW4[k*3+o]; }
    int sw = (o & ((KP >> 3) - 1)) << 3;
    wts[base + (l ^ sw)] = (f16)v;
  } else {                              // ---- bias slab (11 x 128 f32, padded)
    int i = (b - 1460) * 256 + t;
    if (i >= 1408) return;
    int L = i >> 7, o = i & 127;
    float v = 0.f;
    if      (L == 0)            v = mb1[o];
    else if (L == 1)            v = mb2[o];
    else if (L == 2 && o < 32)  v = mb3[o];
    else if (L == 4 && o < 64)  v = pb1[o];
    else if (L == 5 && o < 64)  v = pb2[o];
    else if (L == 6 && o < 16)  v = pb3[o];
    else if (L == 8 && o < 64)  v = db2[o];
    else if (L == 9 && o < 64)  v = db3[o];
    else if (L == 10 && o < 3)  v = db4[o];
    bias[i] = v;
  }
}

// ---- MFMA tile from LDS weights: D[dout-tile dt][sample] = W · B ----
// A/B lane map: row/col = lane&31, k = ks*16 + (lane>>5)*8 + j
// C map (m74/m101): col = lane&31, row = (r&3) + 8*(r>>2) + 4*(lane>>5)
template<int KS>
static __device__ __forceinline__ f32x16 tile_lds(const f16* WL, int wbase,
                                                  int dt, int lane,
                                                  const f16x8* B) {
  const int row = dt*32 + (lane & 31);
  const int sw = (row & (2*KS - 1)) << 3;     // swizzle (elements)
  const int e0 = wbase + row*(KS*16) + (lane >> 5)*8;
  f32x16 acc;
#pragma unroll
  for (int i = 0; i < 16; ++i) acc[i] = 0.f;
#pragma unroll
  for (int ks = 0; ks < KS; ++ks)
    acc = __builtin_amdgcn_mfma_f32_32x32x16_f16(
        *(const f16x8*)(WL + ((e0 + ks*16) ^ sw)), B[ks], acc, 0, 0, 0);
  return acc;
}

// bias add (vectorized: douts for reg r are (r&3)+8*(r>>2)+4g)
template<bool RELU>
static __device__ __forceinline__ void addb(const f32x16& a,
                                            const float* __restrict__ bp,
                                            float* h) {
#pragma unroll
  for (int q = 0; q < 4; ++q) {
    f32x4 b4 = *(const f32x4*)(bp + q*8);
#pragma unroll
    for (int j = 0; j < 4; ++j) {
      float v = a[4*q+j] + b4[j];
      h[4*q+j] = RELU ? fmaxf(v, 0.f) : v;
    }
  }
}

// ---- C-tile (h[16]) -> next-layer B blocks b0/b1. 4 shfl_xor(32). (verified)
static __device__ __forceinline__ void h_to_b(const float* h, int g,
                                              f16x8& b0, f16x8& b1) {
#pragma unroll
  for (int kk = 0; kk < 2; ++kk) {
    unsigned pA0 = pack2(h[8*kk+0], h[8*kk+1]);
    unsigned pA1 = pack2(h[8*kk+2], h[8*kk+3]);
    unsigned pB0 = pack2(h[8*kk+4], h[8*kk+5]);
    unsigned pB1 = pack2(h[8*kk+6], h[8*kk+7]);
    unsigned s0 = g ? pA0 : pB0;
    unsigned s1 = g ? pA1 : pB1;
    unsigned r0 = (unsigned)__shfl_xor((int)s0, 32);
    unsigned r1 = (unsigned)__shfl_xor((int)s1, 32);
    unsigned k0 = g ? pB0 : pA0;
    unsigned k1 = g ? pB1 : pA1;
    f16x8 b = mkb(g ? r0 : k0, g ? r1 : k1, g ? k0 : r0, g ? k1 : r1);
    if (kk == 0) b0 = b; else b1 = b;
  }
}

// ============ kernel 3: barrier-free register-dataflow MLP, LDS weights =======
// 512 threads = 8 independent waves; weights loaded to LDS once; each wave owns
// 32-sample groups end-to-end in registers. __launch_bounds__(512, 2): 2 waves
// per EU -> 256-VGPR budget -> no spill (R11's 128-cap spilled 108 MB).
extern "C" __global__ void __launch_bounds__(512, 2)
k_mlp(const float* __restrict__ rays_o, const float* __restrict__ rays_d,
      const float* __restrict__ grid, const int* __restrict__ slot_map,
      const float2* __restrict__ rayf, const float* __restrict__ embW,
      const f16* __restrict__ wts, const float* __restrict__ bias,
      int* __restrict__ cnt, unsigned short* __restrict__ ws4h) {
  const int total = cnt[0];
  const int ngrp = (total + 31) >> 5;
  int* qh = cnt + 1;
  const int tid = threadIdx.x;
  const int lane = tid & 63;
  const int g = lane >> 5, col = lane & 31;

  __shared__ __align__(16) f16 WL[W_TOT];

  // ---- cooperative weight-slab load (92 KB), once per block ----
  {
    const uint4* src = (const uint4*)wts;
    uint4* dst = (uint4*)WL;
    for (int i = tid; i < W_TOT/8; i += 512) dst[i] = src[i];
  }
  __syncthreads();

  // ---- per-wave dynamic work queue (no block barriers -> safe) ----
  int grp;
  if (lane == 0) grp = atomicAdd(qh, 1);
  grp = __shfl(grp, 0);

  while (grp < ngrp) {
    const int slot = grp*32 + col;

    // ---- interp: this lane loads channels 2g,2g+1 of sample `col` ----
    int pk = -2;
    float m0 = 0.f, m1 = 0.f;
    if (slot < total) {
      int mi = slot_map[slot];
      int ray = mi >> 9, s = mi & 511;
      float2 tf = rayf[ray];
      float ox = rays_o[ray*3+0], oy = rays_o[ray*3+1], oz = rays_o[ray*3+2];
      float dx = rays_d[ray*3+0], dy = rays_d[ray*3+1], dz = rays_d[ray*3+2];
      float px, py, pz;
      sample_point(ox,oy,oz,dx,dy,dz, tf.x, tf.y, s, px,py,pz);
      pk = ray*2 + in_box(px,py,pz);
      float ixf = fminf(fmaxf((px + 1.f) * 0.5f * 255.f, 0.f), 255.f);
      float iyf = fminf(fmaxf((py + 1.f) * 0.5f * 255.f, 0.f), 255.f);
      float izf = fminf(fmaxf((pz + 1.f) * 0.5f * 255.f, 0.f), 255.f);
      int x0 = min((int)ixf, 254), y0 = min((int)iyf, 254), z0 = min((int)izf, 254);
      float fx = ixf - (float)x0, fy = iyf - (float)y0, fz = izf - (float)z0;
      int bx0 = x0 << 16, bx1 = bx0 + 65536;
      int by0 = y0 << 8,  by1 = by0 + 256;
#pragma unroll
      for (int q = 0; q < 2; ++q) {
        const float* gc = grid + (size_t)(2*g + q) * 16777216u;
        float c000 = gc[bx0+by0+z0], c001 = gc[bx0+by0+z0+1];
        float c010 = gc[bx0+by1+z0], c011 = gc[bx0+by1+z0+1];
        float c100 = gc[bx1+by0+z0], c101 = gc[bx1+by0+z0+1];
        float c110 = gc[bx1+by1+z0], c111 = gc[bx1+by1+z0+1];
        float c00 = c000*(1.f-fz) + c001*fz;
        float c01 = c010*(1.f-fz) + c011*fz;
        float c10 = c100*(1.f-fz) + c101*fz;
        float c11 = c110*(1.f-fz) + c111*fz;
        float c0v = c00*(1.f-fy) + c01*fy;
        float c1v = c10*(1.f-fy) + c11*fy;
        float mv = c0v*(1.f-fx) + c1v*fx;
        if (q == 0) m0 = mv; else m1 = mv;
      }
    }
    const int ry = (pk < 0) ? 0 : (pk >> 1);
    float alpha = 0.f;

    // MW1 input B: g=0 lanes hold {c0,c1,c2,c3,0...}; g=1 k-rows are zero wts.
    unsigned xw = pack2(m0, m1);
    unsigned yw = (unsigned)__shfl_xor((int)xw, 32);
    f16x8 bI = mkb(g ? 0u : xw, g ? 0u : yw, 0u, 0u);

    f16x8 P[8], Q[8];
    float h[16];

    // ---- MW1 (16 -> 128), relu ----
#pragma unroll
    for (int dt = 0; dt < 4; ++dt) {
      f32x16 a = tile_lds<1>(WL, W_MW1, dt, lane, &bI);
      addb<true>(a, bias + 0*128 + dt*32 + 4*g, h);
      h_to_b(h, g, P[2*dt], P[2*dt+1]);
    }
    __builtin_amdgcn_sched_barrier(0);

    // ---- MW2 (128 -> 128), relu ----
#pragma unroll
    for (int dt = 0; dt < 4; ++dt) {
      f32x16 a = tile_lds<8>(WL, W_MW2, dt, lane, P);
      addb<true>(a, bias + 1*128 + dt*32 + 4*g, h);
      h_to_b(h, g, Q[2*dt], Q[2*dt+1]);
    }
    __builtin_amdgcn_sched_barrier(0);

    // ---- MW3 (128 -> 32) + in-register softmax ----
    {
      f32x16 a = tile_lds<8>(WL, W_MW3, 0, lane, Q);
      addb<false>(a, bias + 2*128 + 4*g, h);
      float mx = h[0];
#pragma unroll
      for (int r = 1; r < 16; ++r) mx = fmaxf(mx, h[r]);
      mx = fmaxf(mx, __shfl_xor(mx, 32));
      float s = 0.f;
#pragma unroll
      for (int r = 0; r < 16; ++r) { h[r] = expf(h[r] - mx); s += h[r]; }
      s += __shfl_xor(s, 32);
      float inv = 1.f / s;
#pragma unroll
      for (int r = 0; r < 16; ++r) h[r] *= inv;
      h_to_b(h, g, P[0], P[1]);
    }
    __builtin_amdgcn_sched_barrier(0);

    // ---- FV (32 -> 64), no bias/act ----
#pragma unroll
    for (int dt = 0; dt < 2; ++dt) {
      f32x16 a = tile_lds<2>(WL, W_FV, dt, lane, P);
#pragma unroll
      for (int r = 0; r < 16; ++r) h[r] = a[r];
      h_to_b(h, g, Q[2*dt], Q[2*dt+1]);
    }
    __builtin_amdgcn_sched_barrier(0);

    // ---- P1 (64 -> 64), relu ----
#pragma unroll
    for (int dt = 0; dt < 2; ++dt) {
      f32x16 a = tile_lds<4>(WL, W_P1, dt, lane, Q);
      addb<true>(a, bias + 4*128 + dt*32 + 4*g, h);
      h_to_b(h, g, P[2*dt], P[2*dt+1]);
    }
    __builtin_amdgcn_sched_barrier(0);

    // ---- P2 (64 -> 64), relu ----
#pragma unroll
    for (int dt = 0; dt < 2; ++dt) {
      f32x16 a = tile_lds<4>(WL, W_P2, dt, lane, P);
      addb<true>(a, bias + 5*128 + dt*32 + 4*g, h);
      h_to_b(h, g, Q[2*dt], Q[2*dt+1]);
    }
    __builtin_amdgcn_sched_barrier(0);

    // ---- P3 (64 -> 16pad32); alpha from dout0 (g==0, h[0]) ----
    {
      f32x16 a = tile_lds<4>(WL, W_P3, 0, lane, Q);
      addb<false>(a, bias + 6*128 + 4*g, h);
      if (pk >= 0 && (pk & 1)) {
        float x = h[0] + ACT_SHIFT;
        float sp = fmaxf(x, 0.f) + log1pf(expf(-fabsf(x)));
        alpha = 1.f - expf(-sp);
      }
      h_to_b(h, g, P[0], P[1]);
    }
    __builtin_amdgcn_sched_barrier(0);

    // ---- D1 (16 -> 64), relu, per-(ray,dout) embW bias ----
#pragma unroll
    for (int dt = 0; dt < 2; ++dt) {
      f32x16 a = tile_lds<1>(WL, W_D1, dt, lane, P);
      addb<true>(a, embW + (size_t)ry*64 + dt*32 + 4*g, h);
      h_to_b(h, g, Q[2*dt], Q[2*dt+1]);
    }
    __builtin_amdgcn_sched_barrier(0);

    // ---- D2 (64 -> 64), relu ----
#pragma unroll
    for (int dt = 0; dt < 2; ++dt) {
      f32x16 a = tile_lds<4>(WL, W_D2, dt, lane, Q);
      addb<true>(a, bias + 8*128 + dt*32 + 4*g, h);
      h_to_b(h, g, P[2*dt], P[2*dt+1]);
    }
    __builtin_amdgcn_sched_barrier(0);

    // ---- D3 (64 -> 64), relu ----
#pragma unroll
    for (int dt = 0; dt < 2; ++dt) {
      f32x16 a = tile_lds<4>(WL, W_D3, dt, lane, P);
      addb<true>(a, bias + 9*128 + dt*32 + 4*g, h);
      h_to_b(h, g, Q[2*dt], Q[2*dt+1]);
    }
    __builtin_amdgcn_sched_barrier(0);

    // ---- D4 (64 -> 3pad32): rgb head; store (alpha, rgb) ----
    {
      f32x16 a = tile_lds<4>(WL, W_D4, 0, lane, Q);
      if (g == 0 && pk >= 0) {
        bool val = (pk & 1) != 0;
        ushort4 u;
        u.x = f2h(alpha);
        u.y = f2h(val ? 1.f/(1.f+expf(-(a[0] + bias[10*128+0]))) : 0.f);
        u.z = f2h(val ? 1.f/(1.f+expf(-(a[1] + bias[10*128+1]))) : 0.f);
        u.w = f2h(val ? 1.f/(1.f+expf(-(a[2] + bias[10*128+2]))) : 0.f);
        *(ushort4*)(ws4h + (size_t)slot*4) = u;
      }
    }

    if (lane == 0) grp = atomicAdd(qh, 1);
    grp = __shfl(grp, 0);
  }
}

// ============ kernel 4: per-ray transmittance scan over packed slots ==========
extern "C" __global__ void __launch_bounds__(256)
k_scan(const ushort4* __restrict__ ws4h, const int4* __restrict__ rayi,
       float* __restrict__ out) {
  const int wid = (blockIdx.x * 256 + threadIdx.x) >> 6;
  const int ln  = threadIdx.x & 63;
  if (wid >= 4096) return;
  int4 ri = rayi[wid];
  int base = ri.x, n_s = ri.z;

  float T = 1.0f, ar = 0.f, ag = 0.f, ab = 0.f;
  int nc = (n_s + 63) >> 6;
  for (int cck = 0; cck < nc; ++cck) {
    int j = cck*64 + ln;
    float a = 0.f, rr = 0.f, gg = 0.f, bb = 0.f;
    if (j < n_s) {
      ushort4 u = ws4h[(size_t)base + j];
      a = h2f(u.x); rr = h2f(u.y); gg = h2f(u.z); bb = h2f(u.w);
    }
    float p = fmaxf(1.0f - a, 1e-10f);
#pragma unroll
    for (int off = 1; off < 64; off <<= 1) {
      float o = __shfl_up(p, off);
      if (ln >= off) p *= o;
    }
    float pe = __shfl_up(p, 1);
    if (ln == 0) pe = 1.0f;
    float wgt = a * T * pe;
    ar = fmaf(wgt, rr, ar);
    ag = fmaf(wgt, gg, ag);
    ab = fmaf(wgt, bb, ab);
    T *= __shfl(p, 63);
  }
#pragma unroll
  for (int off = 32; off; off >>= 1) {
    ar += __shfl_down(ar, off);
    ag += __shfl_down(ag, off);
    ab += __shfl_down(ab, off);
  }
  if (ln == 0) {
    out[wid*3+0] = ar + T;
    out[wid*3+1] = ag + T;
    out[wid*3+2] = ab + T;
  }
}

extern "C" void kernel_launch(void* const* d_in, const int* in_sizes, int n_in,
                              void* d_out, int out_size, void* d_ws, size_t ws_size,
                              hipStream_t stream) {
  const float* rays_o   = (const float*)d_in[0];
  const float* rays_d   = (const float*)d_in[1];
  const float* viewdirs = (const float*)d_in[2];
  const float* grid     = (const float*)d_in[3];
  const float* fv       = (const float*)d_in[4];
  const float* mW1 = (const float*)d_in[5];  const float* mb1 = (const float*)d_in[6];
  const float* mW2 = (const float*)d_in[7];  const float* mb2 = (const float*)d_in[8];
  const float* mW3 = (const float*)d_in[9];  const float* mb3 = (const float*)d_in[10];
  const float* pW1 = (const float*)d_in[11]; const float* pb1 = (const float*)d_in[12];
  const float* pW2 = (const float*)d_in[13]; const float* pb2 = (const float*)d_in[14];
  const float* pW3 = (const float*)d_in[15]; const float* pb3 = (const float*)d_in[16];
  const float* dW1 = (const float*)d_in[17]; const float* db1 = (const float*)d_in[18];
  const float* dW2 = (const float*)d_in[19]; const float* db2 = (const float*)d_in[20];
  const float* dW3 = (const float*)d_in[21]; const float* db3 = (const float*)d_in[22];
  const float* dW4 = (const float*)d_in[23]; const float* db4 = (const float*)d_in[24];
  float* out = (float*)d_out;

  char* ws = (char*)d_ws;
  int*     cnt      = (int*)(ws + OFF_CNT);
  int4*    rayi     = (int4*)(ws + OFF_RAYI);
  float2*  rayf     = (float2*)(ws + OFF_RAYF);
  float*   embW     = (float*)(ws + OFF_EMBW);
  f16*     wts      = (f16*)(ws + OFF_WTS);
  float*   bias     = (float*)(ws + OFF_BIAS);
  int*     slot_map = (int*)(ws + OFF_SLOT);
  unsigned short* ws4h = (unsigned short*)(ws + OFF_WS4H);

  hipMemsetAsync(cnt, 0, 8, stream);
  k_setup<<<16, 256, 0, stream>>>(rays_o, rays_d, cnt, rayi, rayf);
  k_aux<<<1466, 256, 0, stream>>>(viewdirs, rayi, slot_map,
                                  mW1, mW2, mW3, fv, pW1, pW2, pW3,
                                  dW1, dW2, dW3, dW4,
                                  mb1, mb2, mb3, pb1, pb2, pb3,
                                  db1, db2, db3, db4, wts, bias, embW);
  k_mlp<<<256, 512, 0, stream>>>(rays_o, rays_d, grid, slot_map, rayf,
                                 embW, wts, bias, cnt, ws4h);
  k_scan<<<1024, 256, 0, stream>>>((const ushort4*)ws4h, rayi, out);
}

// Round 13
// 171.138 us; speedup vs baseline: 1.0109x; 1.0109x over previous
//
#include <hip/hip_runtime.h>
#include <math.h>

#define ACT_SHIFT -4.5951198501345889f
#define NSLOTMAX (4096*446)

typedef _Float16 f16;
typedef f16 f16x8 __attribute__((ext_vector_type(8)));
typedef float f32x4 __attribute__((ext_vector_type(4)));
typedef float f32x16 __attribute__((ext_vector_type(16)));

// ---- workspace layout (bytes) ----
#define OFF_CNT  0                          // int cnt, int qhead
#define OFF_RAYI 256                        // int4 * 4096
#define OFF_RAYF (OFF_RAYI + 4096*16)       // float2 * 4096 {tmin, nrm}
#define OFF_EMBW (OFF_RAYF + 4096*8)        // float * 4096*64
#define OFF_WTS  (OFF_EMBW + 4096*64*4)     // f16 * 46080 (XOR-swizzled layout)
#define OFF_BIAS (OFF_WTS + 92160)          // float * 1408 (11 layers x 128)
#define OFF_SLOT (OFF_BIAS + 8192)          // int * NSLOTMAX
#define OFF_WS4H (OFF_SLOT + NSLOTMAX*4)    // ushort4 * NSLOTMAX

// weight slab offsets (f16 elements), Wt[dout][KP] row-major, XOR-swizzled
#define W_MW1 0        /* 128 x 16  */
#define W_MW2 2048     /* 128 x 128 */
#define W_MW3 18432    /* 32  x 128 */
#define W_FV  22528    /* 64  x 32  */
#define W_P1  24576    /* 64  x 64  */
#define W_P2  28672    /* 64  x 64  */
#define W_P3  32768    /* 32  x 64  (douts 16-31 zero-pad) */
#define W_D1  34816    /* 64  x 16  (k=0 zero col) */
#define W_D2  35840    /* 64  x 64  */
#define W_D3  39936    /* 64  x 64  */
#define W_D4  44032    /* 32  x 64  (douts 3-31 zero-pad) */
#define W_TOT 46080

static __device__ __forceinline__ unsigned short f2h(float x) {
  f16 h = (f16)x; return *(unsigned short*)&h;
}
static __device__ __forceinline__ float h2f(unsigned short u) {
  return (float)(*(f16*)&u);
}
static __device__ __forceinline__ unsigned pack2(float a, float b) {
  f16 ha = (f16)a, hb = (f16)b;
  unsigned short ua, ub;
  __builtin_memcpy(&ua, &ha, 2); __builtin_memcpy(&ub, &hb, 2);
  return (unsigned)ua | ((unsigned)ub << 16);
}
static __device__ __forceinline__ f16x8 mkb(unsigned w0, unsigned w1,
                                            unsigned w2, unsigned w3) {
  union { unsigned u[4]; f16x8 h; } x;
  x.u[0] = w0; x.u[1] = w1; x.u[2] = w2; x.u[3] = w3;
  return x.h;
}

static __device__ __forceinline__ void sample_point(
    float ox, float oy, float oz, float dx, float dy, float dz,
    float tmin, float nrm, int s, float& px, float& py, float& pz) {
  float ix = tmin + (0.0078125f * (float)s) / nrm;
  px = ox + dx * ix; py = oy + dy * ix; pz = oz + dz * ix;
}
static __device__ __forceinline__ int in_box(float px, float py, float pz) {
  return !(px < -1.f || px > 1.f || py < -1.f || py > 1.f ||
           pz < -1.f || pz > 1.f);
}

static __device__ __forceinline__ bool ray_setup(
    const float* rays_o, const float* rays_d, int r,
    float& ox, float& oy, float& oz, float& dx, float& dy, float& dz,
    float& tmin, float& nrm) {
  ox = rays_o[r*3+0]; oy = rays_o[r*3+1]; oz = rays_o[r*3+2];
  dx = rays_d[r*3+0]; dy = rays_d[r*3+1]; dz = rays_d[r*3+2];
  const float vx = (dx == 0.0f) ? 1e-6f : dx;
  const float vy = (dy == 0.0f) ? 1e-6f : dy;
  const float vz = (dz == 0.0f) ? 1e-6f : dz;
  const float rax = ( 1.0f - ox) / vx, rbx = (-1.0f - ox) / vx;
  const float ray_ = ( 1.0f - oy) / vy, rby = (-1.0f - oy) / vy;
  const float raz = ( 1.0f - oz) / vz, rbz = (-1.0f - oz) / vz;
  tmin = fmaxf(fmaxf(fminf(rax,rbx), fminf(ray_,rby)), fminf(raz,rbz));
  tmin = fminf(fmaxf(tmin, 0.2f), 3.0f);
  float tmax = fminf(fminf(fmaxf(rax,rbx), fmaxf(ray_,rby)), fmaxf(raz,rbz));
  tmax = fminf(fmaxf(tmax, 0.2f), 3.0f);
  nrm = sqrtf(dx*dx + dy*dy + dz*dz);
  return tmax <= tmin;  // miss
}

// ============ kernel 1: analytic per-ray valid sample range (superset) ========
extern "C" __global__ void __launch_bounds__(256)
k_setup(const float* __restrict__ rays_o, const float* __restrict__ rays_d,
        int* __restrict__ cnt, int4* __restrict__ rayi,
        float2* __restrict__ rayf) {
  int r = blockIdx.x * 256 + threadIdx.x;
  if (r >= 4096) return;
  float ox,oy,oz,dx,dy,dz,tmin,nrm;
  bool miss = ray_setup(rays_o, rays_d, r, ox,oy,oz,dx,dy,dz, tmin, nrm);
  rayf[r] = make_float2(tmin, nrm);
  if (miss) { rayi[r] = make_int4(0,0,0,0); return; }

  float lo = -1e30f, hi = 1e30f;
  float o3[3] = {ox,oy,oz}, d3[3] = {dx,dy,dz};
#pragma unroll
  for (int c = 0; c < 3; ++c) {
    float o = o3[c], d = d3[c];
    if (d == 0.0f) {
      if (o < -1.f || o > 1.f) { lo = 1e30f; hi = -1e30f; }
    } else {
      float t1 = (-1.f - o) / d, t2 = (1.f - o) / d;
      lo = fmaxf(lo, fminf(t1, t2));
      hi = fminf(hi, fmaxf(t1, t2));
    }
  }
  float k = 0.0078125f / nrm;
  float sf = (lo - tmin) / k - 1.0f;
  float lf = (hi - tmin) / k + 1.0f;
  int first = (int)ceilf (fmaxf(0.f,  fminf(445.f, sf)));
  int last  = (int)floorf(fmaxf(-1.f, fminf(445.f, lf)));
  int n_s = (lf >= sf && last >= first) ? (last - first + 1) : 0;
  int base = 0;
  if (n_s > 0) base = atomicAdd(cnt, n_s);
  rayi[r] = make_int4(base, first, n_s, 0);
}

// ============ kernel 2 (fused aux): embW + slot fill + weight/bias pack =======
extern "C" __global__ void __launch_bounds__(256)
k_aux(const float* __restrict__ viewdirs, const int4* __restrict__ rayi,
      int* __restrict__ slot_map,
      const float* __restrict__ mW1, const float* __restrict__ mW2,
      const float* __restrict__ mW3, const float* __restrict__ fv,
      const float* __restrict__ pW1, const float* __restrict__ pW2,
      const float* __restrict__ pW3, const float* __restrict__ dW1,
      const float* __restrict__ dW2, const float* __restrict__ dW3,
      const float* __restrict__ dW4,
      const float* __restrict__ mb1, const float* __restrict__ mb2,
      const float* __restrict__ mb3, const float* __restrict__ pb1,
      const float* __restrict__ pb2, const float* __restrict__ pb3,
      const float* __restrict__ db1, const float* __restrict__ db2,
      const float* __restrict__ db3, const float* __restrict__ db4,
      f16* __restrict__ wts, float* __restrict__ bias,
      float* __restrict__ embW) {
  const int b = blockIdx.x, t = threadIdx.x;
  if (b < 1024) {                       // ---- embW (dir-embed folded into dW1)
    int idx = b * 256 + t;
    int ray = idx >> 6, o = idx & 63;
    float v0 = viewdirs[ray*3+0], v1 = viewdirs[ray*3+1], v2 = viewdirs[ray*3+2];
    float acc = db1[o];
    acc = fmaf(v0, dW1[15*64+o], acc);
    acc = fmaf(v1, dW1[16*64+o], acc);
    acc = fmaf(v2, dW1[17*64+o], acc);
#pragma unroll
    for (int fr = 0; fr < 6; ++fr) {
      float f = (float)(1 << fr);
      int rb = 18 + fr*6;
      acc = fmaf(sinf(v0*f), dW1[(rb+0)*64+o], acc);
      acc = fmaf(sinf(v1*f), dW1[(rb+1)*64+o], acc);
      acc = fmaf(sinf(v2*f), dW1[(rb+2)*64+o], acc);
      acc = fmaf(cosf(v0*f), dW1[(rb+3)*64+o], acc);
      acc = fmaf(cosf(v1*f), dW1[(rb+4)*64+o], acc);
      acc = fmaf(cosf(v2*f), dW1[(rb+5)*64+o], acc);
    }
    embW[idx] = acc;
  } else if (b < 1280) {                // ---- slot_map fill (16 rays/block)
    int ray = (b - 1024) * 16 + (t >> 4);
    int4 ri = rayi[ray];
    for (int i = t & 15; i < ri.z; i += 16)
      slot_map[ri.x + i] = (ray << 9) | (ri.y + i);
  } else if (b < 1460) {                // ---- weight pack, swizzled
    int i = (b - 1280) * 256 + t;
    if (i >= W_TOT) return;
    float v = 0.f; int l, o, k, base, KP;
    if (i < W_MW2)      { base=W_MW1; KP=16;  l=i-base; o=l>>4; k=l&15;  if (k<4)  v = mW1[k*128+o]; }
    else if (i < W_MW3) { base=W_MW2; KP=128; l=i-base; o=l>>7; k=l&127; v = mW2[k*128+o]; }
    else if (i < W_FV)  { base=W_MW3; KP=128; l=i-base; o=l>>7; k=l&127; v = mW3[k*32+o]; }
    else if (i < W_P1)  { base=W_FV;  KP=32;  l=i-base; o=l>>5; k=l&31;  v = fv[k*64+o]; }
    else if (i < W_P2)  { base=W_P1;  KP=64;  l=i-base; o=l>>6; k=l&63;  v = pW1[k*64+o]; }
    else if (i < W_P3)  { base=W_P2;  KP=64;  l=i-base; o=l>>6; k=l&63;  v = pW2[k*64+o]; }
    else if (i < W_D1)  { base=W_P3;  KP=64;  l=i-base; o=l>>6; k=l&63;  if (o<16) v = pW3[k*16+o]; }
    else if (i < W_D2)  { base=W_D1;  KP=16;  l=i-base; o=l>>4; k=l&15;  if (k>=1) v = dW1[(k-1)*64+o]; }
    else if (i < W_D3)  { base=W_D2;  KP=64;  l=i-base; o=l>>6; k=l&63;  v = dW2[k*64+o]; }
    else if (i < W_D4)  { base=W_D3;  KP=64;  l=i-base; o=l>>6; k=l&63;  v = dW3[k*64+o]; }
    else                { base=W_D4;  KP=64;  l=i-base; o=l>>6; k=l&63;  if (o<3)  v = dW4[k*3+o]; }
    int sw = (o & ((KP >> 3) - 1)) << 3;
    wts[base + (l ^ sw)] = (f16)v;
  } else {                              // ---- bias slab (11 x 128 f32, padded)
    int i = (b - 1460) * 256 + t;
    if (i >= 1408) return;
    int L = i >> 7, o = i & 127;
    float v = 0.f;
    if      (L == 0)            v = mb1[o];
    else if (L == 1)            v = mb2[o];
    else if (L == 2 && o < 32)  v = mb3[o];
    else if (L == 4 && o < 64)  v = pb1[o];
    else if (L == 5 && o < 64)  v = pb2[o];
    else if (L == 6 && o < 16)  v = pb3[o];
    else if (L == 8 && o < 64)  v = db2[o];
    else if (L == 9 && o < 64)  v = db3[o];
    else if (L == 10 && o < 3)  v = db4[o];
    bias[i] = v;
  }
}

// ---- MFMA tile from LDS weights: D[dout-tile dt][sample] = W · B ----
// A/B lane map: row/col = lane&31, k = ks*16 + (lane>>5)*8 + j
// C map (m74/m101): col = lane&31, row = (r&3) + 8*(r>>2) + 4*(lane>>5)
template<int KS>
static __device__ __forceinline__ f32x16 tile_lds(const f16* WL, int wbase,
                                                  int dt, int lane,
                                                  const f16x8* B) {
  const int row = dt*32 + (lane & 31);
  const int sw = (row & (2*KS - 1)) << 3;     // swizzle (elements)
  const int e0 = wbase + row*(KS*16) + (lane >> 5)*8;
  f32x16 acc;
#pragma unroll
  for (int i = 0; i < 16; ++i) acc[i] = 0.f;
#pragma unroll
  for (int ks = 0; ks < KS; ++ks)
    acc = __builtin_amdgcn_mfma_f32_32x32x16_f16(
        *(const f16x8*)(WL + ((e0 + ks*16) ^ sw)), B[ks], acc, 0, 0, 0);
  return acc;
}

// bias add (vectorized: douts for reg r are (r&3)+8*(r>>2)+4g)
template<bool RELU>
static __device__ __forceinline__ void addb(const f32x16& a,
                                            const float* __restrict__ bp,
                                            float* h) {
#pragma unroll
  for (int q = 0; q < 4; ++q) {
    f32x4 b4 = *(const f32x4*)(bp + q*8);
#pragma unroll
    for (int j = 0; j < 4; ++j) {
      float v = a[4*q+j] + b4[j];
      h[4*q+j] = RELU ? fmaxf(v, 0.f) : v;
    }
  }
}

// ---- C-tile (h[16]) -> next-layer B blocks b0/b1. 4 shfl_xor(32). (verified)
static __device__ __forceinline__ void h_to_b(const float* h, int g,
                                              f16x8& b0, f16x8& b1) {
#pragma unroll
  for (int kk = 0; kk < 2; ++kk) {
    unsigned pA0 = pack2(h[8*kk+0], h[8*kk+1]);
    unsigned pA1 = pack2(h[8*kk+2], h[8*kk+3]);
    unsigned pB0 = pack2(h[8*kk+4], h[8*kk+5]);
    unsigned pB1 = pack2(h[8*kk+6], h[8*kk+7]);
    unsigned s0 = g ? pA0 : pB0;
    unsigned s1 = g ? pA1 : pB1;
    unsigned r0 = (unsigned)__shfl_xor((int)s0, 32);
    unsigned r1 = (unsigned)__shfl_xor((int)s1, 32);
    unsigned k0 = g ? pB0 : pA0;
    unsigned k1 = g ? pB1 : pA1;
    f16x8 b = mkb(g ? r0 : k0, g ? r1 : k1, g ? k0 : r0, g ? k1 : r1);
    if (kk == 0) b0 = b; else b1 = b;
  }
}

// ============ kernel 3: barrier-free register-dataflow MLP, LDS weights =======
// 512 threads = 8 independent waves; weights loaded to LDS once; each wave owns
// 32-sample groups end-to-end in registers. 92 KB LDS already caps residency at
// 1 block/CU (8 waves = 2/SIMD), so the full 256-VGPR budget is FREE —
// amdgpu_waves_per_eu(1) releases the allocator cap that caused R11/R12's
// 108 MB scratch spill at VGPR=128.
extern "C" __global__
__attribute__((amdgpu_flat_work_group_size(512, 512), amdgpu_waves_per_eu(1)))
void k_mlp(const float* __restrict__ rays_o, const float* __restrict__ rays_d,
      const float* __restrict__ grid, const int* __restrict__ slot_map,
      const float2* __restrict__ rayf, const float* __restrict__ embW,
      const f16* __restrict__ wts, const float* __restrict__ bias,
      int* __restrict__ cnt, unsigned short* __restrict__ ws4h) {
  const int total = cnt[0];
  const int ngrp = (total + 31) >> 5;
  int* qh = cnt + 1;
  const int tid = threadIdx.x;
  const int lane = tid & 63;
  const int g = lane >> 5, col = lane & 31;

  __shared__ __align__(16) f16 WL[W_TOT];

  // ---- cooperative weight-slab load (92 KB), once per block ----
  {
    const uint4* src = (const uint4*)wts;
    uint4* dst = (uint4*)WL;
    for (int i = tid; i < W_TOT/8; i += 512) dst[i] = src[i];
  }
  __syncthreads();

  // ---- per-wave dynamic work queue (no block barriers -> safe) ----
  int grp;
  if (lane == 0) grp = atomicAdd(qh, 1);
  grp = __shfl(grp, 0);

  while (grp < ngrp) {
    const int slot = grp*32 + col;

    // ---- interp: this lane loads channels 2g,2g+1 of sample `col` ----
    int pk = -2;
    float m0 = 0.f, m1 = 0.f;
    if (slot < total) {
      int mi = slot_map[slot];
      int ray = mi >> 9, s = mi & 511;
      float2 tf = rayf[ray];
      float ox = rays_o[ray*3+0], oy = rays_o[ray*3+1], oz = rays_o[ray*3+2];
      float dx = rays_d[ray*3+0], dy = rays_d[ray*3+1], dz = rays_d[ray*3+2];
      float px, py, pz;
      sample_point(ox,oy,oz,dx,dy,dz, tf.x, tf.y, s, px,py,pz);
      pk = ray*2 + in_box(px,py,pz);
      float ixf = fminf(fmaxf((px + 1.f) * 0.5f * 255.f, 0.f), 255.f);
      float iyf = fminf(fmaxf((py + 1.f) * 0.5f * 255.f, 0.f), 255.f);
      float izf = fminf(fmaxf((pz + 1.f) * 0.5f * 255.f, 0.f), 255.f);
      int x0 = min((int)ixf, 254), y0 = min((int)iyf, 254), z0 = min((int)izf, 254);
      float fx = ixf - (float)x0, fy = iyf - (float)y0, fz = izf - (float)z0;
      int bx0 = x0 << 16, bx1 = bx0 + 65536;
      int by0 = y0 << 8,  by1 = by0 + 256;
#pragma unroll
      for (int q = 0; q < 2; ++q) {
        const float* gc = grid + (size_t)(2*g + q) * 16777216u;
        float c000 = gc[bx0+by0+z0], c001 = gc[bx0+by0+z0+1];
        float c010 = gc[bx0+by1+z0], c011 = gc[bx0+by1+z0+1];
        float c100 = gc[bx1+by0+z0], c101 = gc[bx1+by0+z0+1];
        float c110 = gc[bx1+by1+z0], c111 = gc[bx1+by1+z0+1];
        float c00 = c000*(1.f-fz) + c001*fz;
        float c01 = c010*(1.f-fz) + c011*fz;
        float c10 = c100*(1.f-fz) + c101*fz;
        float c11 = c110*(1.f-fz) + c111*fz;
        float c0v = c00*(1.f-fy) + c01*fy;
        float c1v = c10*(1.f-fy) + c11*fy;
        float mv = c0v*(1.f-fx) + c1v*fx;
        if (q == 0) m0 = mv; else m1 = mv;
      }
    }
    const int ry = (pk < 0) ? 0 : (pk >> 1);
    float alpha = 0.f;

    // MW1 input B: g=0 lanes hold {c0,c1,c2,c3,0...}; g=1 k-rows are zero wts.
    unsigned xw = pack2(m0, m1);
    unsigned yw = (unsigned)__shfl_xor((int)xw, 32);
    f16x8 bI = mkb(g ? 0u : xw, g ? 0u : yw, 0u, 0u);

    f16x8 P[8], Q[8];
    float h[16];

    // ---- MW1 (16 -> 128), relu ----
#pragma unroll
    for (int dt = 0; dt < 4; ++dt) {
      f32x16 a = tile_lds<1>(WL, W_MW1, dt, lane, &bI);
      addb<true>(a, bias + 0*128 + dt*32 + 4*g, h);
      h_to_b(h, g, P[2*dt], P[2*dt+1]);
    }
    __builtin_amdgcn_sched_barrier(0);

    // ---- MW2 (128 -> 128), relu ----
#pragma unroll
    for (int dt = 0; dt < 4; ++dt) {
      f32x16 a = tile_lds<8>(WL, W_MW2, dt, lane, P);
      addb<true>(a, bias + 1*128 + dt*32 + 4*g, h);
      h_to_b(h, g, Q[2*dt], Q[2*dt+1]);
    }
    __builtin_amdgcn_sched_barrier(0);

    // ---- MW3 (128 -> 32) + in-register softmax ----
    {
      f32x16 a = tile_lds<8>(WL, W_MW3, 0, lane, Q);
      addb<false>(a, bias + 2*128 + 4*g, h);
      float mx = h[0];
#pragma unroll
      for (int r = 1; r < 16; ++r) mx = fmaxf(mx, h[r]);
      mx = fmaxf(mx, __shfl_xor(mx, 32));
      float s = 0.f;
#pragma unroll
      for (int r = 0; r < 16; ++r) { h[r] = expf(h[r] - mx); s += h[r]; }
      s += __shfl_xor(s, 32);
      float inv = 1.f / s;
#pragma unroll
      for (int r = 0; r < 16; ++r) h[r] *= inv;
      h_to_b(h, g, P[0], P[1]);
    }
    __builtin_amdgcn_sched_barrier(0);

    // ---- FV (32 -> 64), no bias/act ----
#pragma unroll
    for (int dt = 0; dt < 2; ++dt) {
      f32x16 a = tile_lds<2>(WL, W_FV, dt, lane, P);
#pragma unroll
      for (int r = 0; r < 16; ++r) h[r] = a[r];
      h_to_b(h, g, Q[2*dt], Q[2*dt+1]);
    }
    __builtin_amdgcn_sched_barrier(0);

    // ---- P1 (64 -> 64), relu ----
#pragma unroll
    for (int dt = 0; dt < 2; ++dt) {
      f32x16 a = tile_lds<4>(WL, W_P1, dt, lane, Q);
      addb<true>(a, bias + 4*128 + dt*32 + 4*g, h);
      h_to_b(h, g, P[2*dt], P[2*dt+1]);
    }
    __builtin_amdgcn_sched_barrier(0);

    // ---- P2 (64 -> 64), relu ----
#pragma unroll
    for (int dt = 0; dt < 2; ++dt) {
      f32x16 a = tile_lds<4>(WL, W_P2, dt, lane, P);
      addb<true>(a, bias + 5*128 + dt*32 + 4*g, h);
      h_to_b(h, g, Q[2*dt], Q[2*dt+1]);
    }
    __builtin_amdgcn_sched_barrier(0);

    // ---- P3 (64 -> 16pad32); alpha from dout0 (g==0, h[0]) ----
    {
      f32x16 a = tile_lds<4>(WL, W_P3, 0, lane, Q);
      addb<false>(a, bias + 6*128 + 4*g, h);
      if (pk >= 0 && (pk & 1)) {
        float x = h[0] + ACT_SHIFT;
        float sp = fmaxf(x, 0.f) + log1pf(expf(-fabsf(x)));
        alpha = 1.f - expf(-sp);
      }
      h_to_b(h, g, P[0], P[1]);
    }
    __builtin_amdgcn_sched_barrier(0);

    // ---- D1 (16 -> 64), relu, per-(ray,dout) embW bias ----
#pragma unroll
    for (int dt = 0; dt < 2; ++dt) {
      f32x16 a = tile_lds<1>(WL, W_D1, dt, lane, P);
      addb<true>(a, embW + (size_t)ry*64 + dt*32 + 4*g, h);
      h_to_b(h, g, Q[2*dt], Q[2*dt+1]);
    }
    __builtin_amdgcn_sched_barrier(0);

    // ---- D2 (64 -> 64), relu ----
#pragma unroll
    for (int dt = 0; dt < 2; ++dt) {
      f32x16 a = tile_lds<4>(WL, W_D2, dt, lane, Q);
      addb<true>(a, bias + 8*128 + dt*32 + 4*g, h);
      h_to_b(h, g, P[2*dt], P[2*dt+1]);
    }
    __builtin_amdgcn_sched_barrier(0);

    // ---- D3 (64 -> 64), relu ----
#pragma unroll
    for (int dt = 0; dt < 2; ++dt) {
      f32x16 a = tile_lds<4>(WL, W_D3, dt, lane, P);
      addb<true>(a, bias + 9*128 + dt*32 + 4*g, h);
      h_to_b(h, g, Q[2*dt], Q[2*dt+1]);
    }
    __builtin_amdgcn_sched_barrier(0);

    // ---- D4 (64 -> 3pad32): rgb head; store (alpha, rgb) ----
    {
      f32x16 a = tile_lds<4>(WL, W_D4, 0, lane, Q);
      if (g == 0 && pk >= 0) {
        bool val = (pk & 1) != 0;
        ushort4 u;
        u.x = f2h(alpha);
        u.y = f2h(val ? 1.f/(1.f+expf(-(a[0] + bias[10*128+0]))) : 0.f);
        u.z = f2h(val ? 1.f/(1.f+expf(-(a[1] + bias[10*128+1]))) : 0.f);
        u.w = f2h(val ? 1.f/(1.f+expf(-(a[2] + bias[10*128+2]))) : 0.f);
        *(ushort4*)(ws4h + (size_t)slot*4) = u;
      }
    }

    if (lane == 0) grp = atomicAdd(qh, 1);
    grp = __shfl(grp, 0);
  }
}

// ============ kernel 4: per-ray transmittance scan over packed slots ==========
extern "C" __global__ void __launch_bounds__(256)
k_scan(const ushort4* __restrict__ ws4h, const int4* __restrict__ rayi,
       float* __restrict__ out) {
  const int wid = (blockIdx.x * 256 + threadIdx.x) >> 6;
  const int ln  = threadIdx.x & 63;
  if (wid >= 4096) return;
  int4 ri = rayi[wid];
  int base = ri.x, n_s = ri.z;

  float T = 1.0f, ar = 0.f, ag = 0.f, ab = 0.f;
  int nc = (n_s + 63) >> 6;
  for (int cck = 0; cck < nc; ++cck) {
    int j = cck*64 + ln;
    float a = 0.f, rr = 0.f, gg = 0.f, bb = 0.f;
    if (j < n_s) {
      ushort4 u = ws4h[(size_t)base + j];
      a = h2f(u.x); rr = h2f(u.y); gg = h2f(u.z); bb = h2f(u.w);
    }
    float p = fmaxf(1.0f - a, 1e-10f);
#pragma unroll
    for (int off = 1; off < 64; off <<= 1) {
      float o = __shfl_up(p, off);
      if (ln >= off) p *= o;
    }
    float pe = __shfl_up(p, 1);
    if (ln == 0) pe = 1.0f;
    float wgt = a * T * pe;
    ar = fmaf(wgt, rr, ar);
    ag = fmaf(wgt, gg, ag);
    ab = fmaf(wgt, bb, ab);
    T *= __shfl(p, 63);
  }
#pragma unroll
  for (int off = 32; off; off >>= 1) {
    ar += __shfl_down(ar, off);
    ag += __shfl_down(ag, off);
    ab += __shfl_down(ab, off);
  }
  if (ln == 0) {
    out[wid*3+0] = ar + T;
    out[wid*3+1] = ag + T;
    out[wid*3+2] = ab + T;
  }
}

extern "C" void kernel_launch(void* const* d_in, const int* in_sizes, int n_in,
                              void* d_out, int out_size, void* d_ws, size_t ws_size,
                              hipStream_t stream) {
  const float* rays_o   = (const float*)d_in[0];
  const float* rays_d   = (const float*)d_in[1];
  const float* viewdirs = (const float*)d_in[2];
  const float* grid     = (const float*)d_in[3];
  const float* fv       = (const float*)d_in[4];
  const float* mW1 = (const float*)d_in[5];  const float* mb1 = (const float*)d_in[6];
  const float* mW2 = (const float*)d_in[7];  const float* mb2 = (const float*)d_in[8];
  const float* mW3 = (const float*)d_in[9];  const float* mb3 = (const float*)d_in[10];
  const float* pW1 = (const float*)d_in[11]; const float* pb1 = (const float*)d_in[12];
  const float* pW2 = (const float*)d_in[13]; const float* pb2 = (const float*)d_in[14];
  const float* pW3 = (const float*)d_in[15]; const float* pb3 = (const float*)d_in[16];
  const float* dW1 = (const float*)d_in[17]; const float* db1 = (const float*)d_in[18];
  const float* dW2 = (const float*)d_in[19]; const float* db2 = (const float*)d_in[20];
  const float* dW3 = (const float*)d_in[21]; const float* db3 = (const float*)d_in[22];
  const float* dW4 = (const float*)d_in[23]; const float* db4 = (const float*)d_in[24];
  float* out = (float*)d_out;

  char* ws = (char*)d_ws;
  int*     cnt      = (int*)(ws + OFF_CNT);
  int4*    rayi     = (int4*)(ws + OFF_RAYI);
  float2*  rayf     = (float2*)(ws + OFF_RAYF);
  float*   embW     = (float*)(ws + OFF_EMBW);
  f16*     wts      = (f16*)(ws + OFF_WTS);
  float*   bias     = (float*)(ws + OFF_BIAS);
  int*     slot_map = (int*)(ws + OFF_SLOT);
  unsigned short* ws4h = (unsigned short*)(ws + OFF_WS4H);

  hipMemsetAsync(cnt, 0, 8, stream);
  k_setup<<<16, 256, 0, stream>>>(rays_o, rays_d, cnt, rayi, rayf);
  k_aux<<<1466, 256, 0, stream>>>(viewdirs, rayi, slot_map,
                                  mW1, mW2, mW3, fv, pW1, pW2, pW3,
                                  dW1, dW2, dW3, dW4,
                                  mb1, mb2, mb3, pb1, pb2, pb3,
                                  db1, db2, db3, db4, wts, bias, embW);
  k_mlp<<<256, 512, 0, stream>>>(rays_o, rays_d, grid, slot_map, rayf,
                                 embW, wts, bias, cnt, ws4h);
  k_scan<<<1024, 256, 0, stream>>>((const ushort4*)ws4h, rayi, out);
}